// Round 11
// baseline (196.516 us; speedup 1.0000x reference)
//
#include <hip/hip_runtime.h>

#define NXD 128
#define NYD 128
#define SRC_XD 64
#define SRC_YD 64
#define T_STEPSD 256
#define BATCHD 8
#define N_PROBESD 4

typedef float v2f __attribute__((ext_vector_type(2)));

// DPP cross-lane single shifts across the full wave64 (zero-fill = conv SAME).
__device__ __forceinline__ float dpp_from_lower(float v) {
    return __int_as_float(__builtin_amdgcn_update_dpp(0, __float_as_int(v), 0x138, 0xF, 0xF, true));
}
__device__ __forceinline__ float dpp_from_upper(float v) {
    return __int_as_float(__builtin_amdgcn_update_dpp(0, __float_as_int(v), 0x130, 0xF, 0xF, true));
}

// Capture lane srcl's value of v into lane dstl of trace register tr.
// (r8: no writelane builtin; r9: asm writelane hits the 1-SGPR constant-bus
// rule. readlane broadcast + predicated move compiles clean and fast.)
__device__ __forceinline__ void lane_store(float& tr, float v, int srcl, int dstl, int l) {
    const float sv = __int_as_float(__builtin_amdgcn_readlane(__float_as_int(v), srcl));
    if (l == dstl) tr = sv;
}

// ======================= SPECTRAL PATH (c == 1) =======================
// Reference step: y' = (2.0 + dt^2 lap(y1) - (1+dt*b) y2)/denom  (+src);
// the 2.0 is a CONSTANT FIELD. DST-I in x diagonalizes; one wave64 per
// (mode kx, batch), 2 cols/lane, DPP column stencil, no barriers in-loop.
// r7 lesson: per-step agent-scope atomics = memory-side RMWs (65 us).
// r10 lesson: the pipeline's top dispatch was a 39 us buffer FILL -- so this
// round removes ALL zero-init requirements: probe traces live in registers
// (lane t&63 via readlane+predicated move), spill to LDS per 64-step chunk,
// block-reduce its 4 modes wx-weighted, and store UNCONDITIONALLY to a
// private per-block pbuf region (no atomics, no memset). 3 dispatches total.

__global__ __launch_bounds__(256) void spectral_evolve(
        const float* __restrict__ x,        // (T,B)
        const int*   __restrict__ probes,   // (4,2) int32
        float*       __restrict__ pbuf)     // (256 blocks,16,64) private
{
    __shared__ float xls[T_STEPSD + 2];
    __shared__ float ltr[4][N_PROBESD][4][64];  // [wave][probe][chunk][lane] 16KB
    __shared__ float lwx[4][N_PROBESD];         // per-wave probe weights

    const int tid = threadIdx.x;
    const int l = tid & 63;
    const int wid = tid >> 6;
    const int wg = blockIdx.x * 4 + wid;         // global wave id 0..1023
    const int bb = blockIdx.x >> 5;              // batch (block-uniform: 4|128)
    const int kx = wg & 127;                     // mode index (wave-uniform)

    if (tid < T_STEPSD) xls[tid] = x[tid * BATCHD + bb];
    if (tid < 2) xls[T_STEPSD + tid] = 0.0f;     // pad for 2-ahead prefetch

    const float dt = 0.5f, bd = 0.005f;
    const float denom = 1.0f / (dt * dt) + 0.5f * bd / dt;   // 4.005
    const int m = kx + 1;
    // lam = -4 sin^2(pi m/258)
    const float s1 = sinpif((float)m / 258.0f);
    const float lam = -4.0f * s1 * s1;
    const float C1s = (dt * dt * (lam - 2.0f)) / denom;
    const float C3s = (dt * dt) / denom;
    const float C2s = -(1.0f + dt * bd) / denom;
    // constant-field forcing (transform of the "+2.0" term)
    const float g = (m & 1) ? (2.0f / 129.0f) *
                    (cospif((float)m / 258.0f) / sinpif((float)m / 258.0f)) : 0.0f;
    const float fk = 2.0f * g / denom;
    // source coefficient
    const float bk = (2.0f / 129.0f) *
                     sinpif((float)((m * (SRC_XD + 1)) % 258) / 129.0f);

    v2f C1v; C1v.x = C1s; C1v.y = C1s;
    v2f C3v; C3v.x = C3s; C3v.y = C3s;
    v2f C2v; C2v.x = C2s; C2v.y = C2s;
    v2f fv;  fv.x = fk;  fv.y = fk;
    v2f zz;  zz.x = 0.0f; zz.y = 0.0f;
    v2f svec = zz; if (l == (SRC_YD >> 1)) svec.x = bk;   // col 64 = lane32.x

    // probes (int32 pairs; JAX int64 demotes to int32 without x64)
    const int px0 = probes[0] & 127, py0 = probes[1] & 127;
    const int px1 = probes[2] & 127, py1 = probes[3] & 127;
    const int px2 = probes[4] & 127, py2 = probes[5] & 127;
    const int px3 = probes[6] & 127, py3 = probes[7] & 127;
    if (l == 0) {
        lwx[wid][0] = sinpif((float)((m * (px0 + 1)) % 258) / 129.0f);
        lwx[wid][1] = sinpif((float)((m * (px1 + 1)) % 258) / 129.0f);
        lwx[wid][2] = sinpif((float)((m * (px2 + 1)) % 258) / 129.0f);
        lwx[wid][3] = sinpif((float)((m * (px3 + 1)) % 258) / 129.0f);
    }
    const int pyl0 = __builtin_amdgcn_readfirstlane(py0 >> 1), pel0 = py0 & 1;
    const int pyl1 = __builtin_amdgcn_readfirstlane(py1 >> 1), pel1 = py1 & 1;
    const int pyl2 = __builtin_amdgcn_readfirstlane(py2 >> 1), pel2 = py2 & 1;
    const int pyl3 = __builtin_amdgcn_readfirstlane(py3 >> 1), pel3 = py3 & 1;

    __syncthreads();

    v2f u = zz, uo = zz;
    v2f xc; xc.x = xls[0]; xc.y = xls[1];
    float tr0 = 0.0f, tr1 = 0.0f, tr2 = 0.0f, tr3 = 0.0f;

#define SSTEP(xv, tl_) { \
    const float lf = dpp_from_lower(u.y); \
    const float rt = dpp_from_upper(u.x); \
    v2f cross; cross.x = lf + u.y; cross.y = u.x + rt; \
    const v2f r = C1v * u + C3v * cross + C2v * uo + svec * (xv) + fv; \
    uo = u; u = r; \
    lane_store(tr0, pel0 ? u.y : u.x, pyl0, (tl_), l); \
    lane_store(tr1, pel1 ? u.y : u.x, pyl1, (tl_), l); \
    lane_store(tr2, pel2 ? u.y : u.x, pyl2, (tl_), l); \
    lane_store(tr3, pel3 ? u.y : u.x, pyl3, (tl_), l); \
}

#pragma unroll 1
    for (int t = 0; t < T_STEPSD; t += 2) {
        const v2f xn = *(const v2f*)&xls[t + 2];   // 2-ahead: hides ds latency
        const int tl = t & 63;
        SSTEP(xc.x, tl)
        SSTEP(xc.y, tl + 1)
        xc = xn;
        if (tl == 62) {                            // chunk (t>>6) complete
            const int ch = t >> 6;
            ltr[wid][0][ch][l] = tr0;
            ltr[wid][1][ch][l] = tr1;
            ltr[wid][2][ch][l] = tr2;
            ltr[wid][3][ch][l] = tr3;
        }
    }
#undef SSTEP

    __syncthreads();

    // Block reduces its 4 modes (wx-weighted) and stores UNCONDITIONALLY to
    // its private pbuf region -- no init required, no atomics, idempotent.
#pragma unroll
    for (int r = 0; r < 4; ++r) {
        const int jc = (tid >> 6) + r * 4;         // j = jc&3, ch = jc>>2
        const int j = jc & 3, ch = jc >> 2;
        const float s = lwx[0][j] * ltr[0][j][ch][l]
                      + lwx[1][j] * ltr[1][j][ch][l]
                      + lwx[2][j] * ltr[2][j][ch][l]
                      + lwx[3][j] * ltr[3][j][ch][l];
        pbuf[((size_t)blockIdx.x * 16 + jc) * 64 + l] = s;
    }
}

// Single final kernel: spectral case sums the 32 q-regions per (j,b,t),
// square-sums, normalizes, writes out. Fallback case reduces partial.
__global__ __launch_bounds__(1024) void spectral_final(
        const float* __restrict__ pbuf, const float* __restrict__ partial,
        const int* __restrict__ flag, float* __restrict__ out)
{
    __shared__ float sm[32];
    const int tid = threadIdx.x;
    if (*flag == 0) {
        const int jb = tid >> 5;            // 0..31: j = jb>>3, b = jb&7
        const int j = jb >> 3, b = jb & 7;
        const int ln = tid & 31;
        float acc = 0.0f;
#pragma unroll
        for (int i = 0; i < 8; ++i) {
            const int t = ln * 8 + i;
            const int ch = t >> 6, l = t & 63;
            float v = 0.0f;
#pragma unroll 8
            for (int q = 0; q < 32; ++q)
                v += pbuf[(((size_t)(b * 32 + q)) * 16 + ch * 4 + j) * 64 + l];
            acc += v * v;
        }
        for (int off = 16; off; off >>= 1) acc += __shfl_down(acc, off, 32);
        if (ln == 0) sm[jb] = acc;          // sm[j*8+b] = per-(probe,batch) sum
        __syncthreads();
        if (tid < N_PROBESD) {
            float s = 0.0f, tot = 0.0f;
            for (int b2 = 0; b2 < BATCHD; ++b2) s += sm[tid * 8 + b2];
            for (int i2 = 0; i2 < 32; ++i2) tot += sm[i2];
            out[tid] = s / tot;
        }
    } else {
        if (tid < N_PROBESD) {
            float s = 0.0f, tot = 0.0f;
            for (int b2 = 0; b2 < BATCHD; ++b2) s += partial[b2 * N_PROBESD + tid];
            for (int i2 = 0; i2 < BATCHD * N_PROBESD; ++i2) tot += partial[i2];
            out[tid] = s / tot;
        }
    }
}

// ================= FDTD PATH (arbitrary c): round-4 kernel =================
// When flag != nullptr it ALSO performs the c-uniformity check (all blocks
// compute the same verdict; same-value flag store race is benign) and
// early-exits if c == 1 everywhere (spectral path owns the answer).
#define ROW(up, dn, Yr, Zr, Kr) { \
    const float lf = dpp_from_lower((Yr).y); \
    const float rt = dpp_from_upper((Yr).x); \
    v2f cross; cross.x = lf + (Yr).y; cross.y = (Yr).x + rt; \
    const v2f lap = (up) + (dn) + cross - 4.0f * (Yr); \
    (Zr) = (Kr) * lap + (C2v + K2v * (Zr)); \
}

#define PSEL8(ro, Z, pv) switch (ro) { \
    case 0: pv = (Z##0); break; case 1: pv = (Z##1); break; \
    case 2: pv = (Z##2); break; case 3: pv = (Z##3); break; \
    case 4: pv = (Z##4); break; case 5: pv = (Z##5); break; \
    case 6: pv = (Z##6); break; default: pv = (Z##7); break; }

#define STEP8(Y, Z, tt, xsv) { \
    const int buf_ = (tt) & 1, nb_ = buf_ ^ 1; \
    const v2f ra = *(const v2f*)&haloBot[buf_][wa][colb]; \
    const v2f rb = *(const v2f*)&haloTop[buf_][wb][colb]; \
    ROW(Y##1,  Y##3,  Y##2,  Z##2,  k2) \
    ROW(Y##2,  Y##4,  Y##3,  Z##3,  k3) \
    ROW(Y##3,  Y##5,  Y##4,  Z##4,  k4) \
    ROW(ra,    Y##1,  Y##0,  Z##0,  k0) \
    if (has_src) { if (own_src) (Z##0).x += (xsv); } \
    *(v2f*)&haloTop[nb_][w][colb] = (Z##0); \
    ROW(Y##6,  rb,    Y##7,  Z##7,  k7) \
    *(v2f*)&haloBot[nb_][w][colb] = (Z##7); \
    ROW(Y##0,  Y##2,  Y##1,  Z##1,  k1) \
    ROW(Y##4,  Y##6,  Y##5,  Z##5,  k5) \
    ROW(Y##5,  Y##7,  Y##6,  Z##6,  k6) \
    if (anyprobe) { \
        acc8_0 += (Z##0) * (Z##0); acc8_1 += (Z##1) * (Z##1); \
        acc8_2 += (Z##2) * (Z##2); acc8_3 += (Z##3) * (Z##3); \
        acc8_4 += (Z##4) * (Z##4); acc8_5 += (Z##5) * (Z##5); \
        acc8_6 += (Z##6) * (Z##6); acc8_7 += (Z##7) * (Z##7); \
    } \
    __syncthreads(); \
}

__global__ __launch_bounds__(1024, 4) void wave_sim_full(
        const float* __restrict__ x, const float* __restrict__ c,
        const int* __restrict__ probes, float* __restrict__ partial,
        int* __restrict__ flag)
{
    const int tid = threadIdx.x;

    if (flag) {
        // c-uniformity check: block-uniform verdict, early-exit if spectral.
        __shared__ int wbad[16];
        __shared__ int bad_sh;
        bool bad = false;
        for (int i = tid; i < NXD * NYD; i += 1024) bad |= (c[i] != 1.0f);
        const unsigned long long wb_ = __ballot(bad);
        if ((tid & 63) == 0) wbad[tid >> 6] = (wb_ != 0ULL) ? 1 : 0;
        __syncthreads();
        if (tid == 0) {
            int f = 0;
            for (int i = 0; i < 16; ++i) f |= wbad[i];
            bad_sh = f;
            *flag = f;                  // all blocks store the same value
        }
        __syncthreads();
        if (bad_sh == 0) return;        // spectral path owns the answer
    }

    __shared__ float haloTop[2][17][NYD];
    __shared__ float haloBot[2][17][NYD];
    __shared__ float xs[T_STEPSD];

    const int w = tid >> 6;
    const int l = tid & 63;
    const int b = blockIdx.x;

    const float dt = 0.5f, bdamp = 0.005f;
    const float denom = 1.0f / (dt * dt) + 0.5f * bdamp / dt;
    const float inv_denom = 1.0f / denom;
    const float C2 = 2.0f * inv_denom;
    const float K2 = (-1.0f - dt * bdamp) * inv_denom;
    const float KL = dt * dt * inv_denom;
    v2f C2v; C2v.x = C2; C2v.y = C2;
    v2f K2v; K2v.x = K2; K2v.y = K2;

    for (int i = tid; i < 2 * 17 * NYD; i += 1024) {
        ((float*)haloTop)[i] = 0.0f;
        ((float*)haloBot)[i] = 0.0f;
    }
    if (tid < T_STEPSD) xs[tid] = x[tid * BATCHD + b];

    const int rowbase = w * 8;
    const int colb = 2 * l;
#define LOADK(r) \
    v2f k##r; { \
        const v2f cc = *(const v2f*)&c[(rowbase + r) * NYD + colb]; \
        k##r = KL * cc * cc; \
    }
    LOADK(0) LOADK(1) LOADK(2) LOADK(3) LOADK(4) LOADK(5) LOADK(6) LOADK(7)
#undef LOADK

    v2f zz; zz.x = 0.0f; zz.y = 0.0f;
    v2f a0 = zz, a1 = zz, a2 = zz, a3 = zz, a4 = zz, a5 = zz, a6 = zz, a7 = zz;
    v2f b0 = zz, b1 = zz, b2 = zz, b3 = zz, b4 = zz, b5 = zz, b6 = zz, b7 = zz;
    v2f acc8_0 = zz, acc8_1 = zz, acc8_2 = zz, acc8_3 = zz,
        acc8_4 = zz, acc8_5 = zz, acc8_6 = zz, acc8_7 = zz;

    const int px0 = probes[0] & 127, py0 = probes[1] & 127;
    const int px1 = probes[2] & 127, py1 = probes[3] & 127;
    const int px2 = probes[4] & 127, py2 = probes[5] & 127;
    const int px3 = probes[6] & 127, py3 = probes[7] & 127;
    const bool own0 = ((px0 >> 3) == w) && ((py0 >> 1) == l);
    const bool own1 = ((px1 >> 3) == w) && ((py1 >> 1) == l);
    const bool own2 = ((px2 >> 3) == w) && ((py2 >> 1) == l);
    const bool own3 = ((px3 >> 3) == w) && ((py3 >> 1) == l);
    const bool anyprobe = __ballot(own0 | own1 | own2 | own3) != 0ULL;
    const int pro0s = __builtin_amdgcn_readfirstlane(px0 & 7);
    const int pro1s = __builtin_amdgcn_readfirstlane(px1 & 7);
    const int pro2s = __builtin_amdgcn_readfirstlane(px2 & 7);
    const int pro3s = __builtin_amdgcn_readfirstlane(px3 & 7);
    const int pel0 = py0 & 1, pel1 = py1 & 1, pel2 = py2 & 1, pel3 = py3 & 1;

    const bool has_src = (w == (SRC_XD >> 3));
    const bool own_src = has_src && (l == (SRC_YD >> 1));

    const int wa = (w == 0) ? 16 : w - 1;
    const int wb = (w == 15) ? 16 : w + 1;

    __syncthreads();

#pragma unroll 1
    for (int t = 0; t < T_STEPSD; t += 2) {
        const v2f xp = *(const v2f*)&xs[t];
        STEP8(a, b, t, xp.x)
        STEP8(b, a, t + 1, xp.y)
    }

    if (own0) { v2f pv; PSEL8(pro0s, acc8_, pv) partial[b * N_PROBESD + 0] = pel0 ? pv.y : pv.x; }
    if (own1) { v2f pv; PSEL8(pro1s, acc8_, pv) partial[b * N_PROBESD + 1] = pel1 ? pv.y : pv.x; }
    if (own2) { v2f pv; PSEL8(pro2s, acc8_, pv) partial[b * N_PROBESD + 2] = pel2 ? pv.y : pv.x; }
    if (own3) { v2f pv; PSEL8(pro3s, acc8_, pv) partial[b * N_PROBESD + 3] = pel3 ? pv.y : pv.x; }
}

__global__ void reduce_k(const float* __restrict__ partial, float* __restrict__ out) {
    const int p = threadIdx.x;
    if (p < N_PROBESD) {
        float s = 0.0f, tot = 0.0f;
        for (int bb = 0; bb < BATCHD; ++bb) s += partial[bb * N_PROBESD + p];
        for (int i = 0; i < BATCHD * N_PROBESD; ++i) tot += partial[i];
        out[p] = s / tot;
    }
}

// d_ws layout (spectral path): [0..4) flag | [256..256+1MB) pbuf (256*16*64 f32,
// written unconditionally -- NO memset anywhere) | then partial (32 f32).
extern "C" void kernel_launch(void* const* d_in, const int* in_sizes, int n_in,
                              void* d_out, int out_size, void* d_ws, size_t ws_size,
                              hipStream_t stream) {
    const float* x      = (const float*)d_in[0];
    const float* c      = (const float*)d_in[1];
    const int*   probes = (const int*)d_in[2];
    float* out = (float*)d_out;

    const size_t pbuf_off = 256;
    const size_t pbuf_bytes = (size_t)256 * 16 * 64 * sizeof(float);   // 1 MB
    const size_t part_off = pbuf_off + pbuf_bytes;
    const size_t need = part_off + 32 * sizeof(float);
    if (ws_size >= need) {
        int*   flag    = (int*)d_ws;
        float* pbuf    = (float*)((char*)d_ws + pbuf_off);
        float* partial = (float*)((char*)d_ws + part_off);
        spectral_evolve<<<256, 256, 0, stream>>>(x, probes, pbuf);
        wave_sim_full<<<BATCHD, 1024, 0, stream>>>(x, c, probes, partial, flag);
        spectral_final<<<1, 1024, 0, stream>>>(pbuf, partial, flag, out);
    } else {
        float* partial = (float*)d_ws;
        wave_sim_full<<<BATCHD, 1024, 0, stream>>>(x, c, probes, partial, nullptr);
        reduce_k<<<1, 64, 0, stream>>>(partial, out);
    }
}

// Round 12
// 90.438 us; speedup vs baseline: 2.1729x; 2.1729x over previous
//
#include <hip/hip_runtime.h>

#define NXD 128
#define NYD 128
#define SRC_XD 64
#define SRC_YD 64
#define T_STEPSD 256
#define BATCHD 8
#define N_PROBESD 4

typedef float v2f __attribute__((ext_vector_type(2)));

// DPP cross-lane single shifts across the full wave64 (zero-fill = conv SAME).
__device__ __forceinline__ float dpp_from_lower(float v) {
    return __int_as_float(__builtin_amdgcn_update_dpp(0, __float_as_int(v), 0x138, 0xF, 0xF, true));
}
__device__ __forceinline__ float dpp_from_upper(float v) {
    return __int_as_float(__builtin_amdgcn_update_dpp(0, __float_as_int(v), 0x130, 0xF, 0xF, true));
}

// Capture lane srcl's value of v into lane dstl of trace register tr.
// (r8: no writelane builtin; r9: asm writelane hits the 1-SGPR constant-bus
// rule. readlane broadcast + predicated move compiles clean and fast.)
__device__ __forceinline__ void lane_store(float& tr, float v, int srcl, int dstl, int l) {
    const float sv = __int_as_float(__builtin_amdgcn_readlane(__float_as_int(v), srcl));
    if (l == dstl) tr = sv;
}

// ======================= SPECTRAL PATH (c == 1) =======================
// Reference step: y' = (2.0 + dt^2 lap(y1) - (1+dt*b) y2)/denom  (+src);
// the 2.0 is a CONSTANT FIELD. DST-I in x diagonalizes; one wave64 per
// (mode kx, batch), 2 cols/lane, DPP column stencil, no barriers in-loop.
// Probe traces in registers (lane t&63 via readlane+predicated move), LDS
// spill per 64-step chunk, block-reduce 4 modes wx-weighted, unconditional
// private pbuf stores (no memset, no atomics).
// r11 lesson: the cross-q reduction must be PARALLEL -- a 1-block final
// reading 1 MB scattered was 114 us (latency-bound, 0.18% occupancy).

__global__ __launch_bounds__(256) void spectral_evolve(
        const float* __restrict__ x,        // (T,B)
        const int*   __restrict__ probes,   // (4,2) int32
        float*       __restrict__ pbuf)     // (256 blocks,16,64) private
{
    __shared__ float xls[T_STEPSD + 2];
    __shared__ float ltr[4][N_PROBESD][4][64];  // [wave][probe][chunk][lane] 16KB
    __shared__ float lwx[4][N_PROBESD];         // per-wave probe weights

    const int tid = threadIdx.x;
    const int l = tid & 63;
    const int wid = tid >> 6;
    const int wg = blockIdx.x * 4 + wid;         // global wave id 0..1023
    const int bb = blockIdx.x >> 5;              // batch (block-uniform: 4|128)
    const int kx = wg & 127;                     // mode index (wave-uniform)

    if (tid < T_STEPSD) xls[tid] = x[tid * BATCHD + bb];
    if (tid < 2) xls[T_STEPSD + tid] = 0.0f;     // pad for 2-ahead prefetch

    const float dt = 0.5f, bd = 0.005f;
    const float denom = 1.0f / (dt * dt) + 0.5f * bd / dt;   // 4.005
    const int m = kx + 1;
    // lam = -4 sin^2(pi m/258)
    const float s1 = sinpif((float)m / 258.0f);
    const float lam = -4.0f * s1 * s1;
    const float C1s = (dt * dt * (lam - 2.0f)) / denom;
    const float C3s = (dt * dt) / denom;
    const float C2s = -(1.0f + dt * bd) / denom;
    // constant-field forcing (transform of the "+2.0" term)
    const float g = (m & 1) ? (2.0f / 129.0f) *
                    (cospif((float)m / 258.0f) / sinpif((float)m / 258.0f)) : 0.0f;
    const float fk = 2.0f * g / denom;
    // source coefficient
    const float bk = (2.0f / 129.0f) *
                     sinpif((float)((m * (SRC_XD + 1)) % 258) / 129.0f);

    v2f C1v; C1v.x = C1s; C1v.y = C1s;
    v2f C3v; C3v.x = C3s; C3v.y = C3s;
    v2f C2v; C2v.x = C2s; C2v.y = C2s;
    v2f fv;  fv.x = fk;  fv.y = fk;
    v2f zz;  zz.x = 0.0f; zz.y = 0.0f;
    v2f svec = zz; if (l == (SRC_YD >> 1)) svec.x = bk;   // col 64 = lane32.x

    // probes (int32 pairs; JAX int64 demotes to int32 without x64)
    const int px0 = probes[0] & 127, py0 = probes[1] & 127;
    const int px1 = probes[2] & 127, py1 = probes[3] & 127;
    const int px2 = probes[4] & 127, py2 = probes[5] & 127;
    const int px3 = probes[6] & 127, py3 = probes[7] & 127;
    if (l == 0) {
        lwx[wid][0] = sinpif((float)((m * (px0 + 1)) % 258) / 129.0f);
        lwx[wid][1] = sinpif((float)((m * (px1 + 1)) % 258) / 129.0f);
        lwx[wid][2] = sinpif((float)((m * (px2 + 1)) % 258) / 129.0f);
        lwx[wid][3] = sinpif((float)((m * (px3 + 1)) % 258) / 129.0f);
    }
    const int pyl0 = __builtin_amdgcn_readfirstlane(py0 >> 1), pel0 = py0 & 1;
    const int pyl1 = __builtin_amdgcn_readfirstlane(py1 >> 1), pel1 = py1 & 1;
    const int pyl2 = __builtin_amdgcn_readfirstlane(py2 >> 1), pel2 = py2 & 1;
    const int pyl3 = __builtin_amdgcn_readfirstlane(py3 >> 1), pel3 = py3 & 1;

    __syncthreads();

    v2f u = zz, uo = zz;
    v2f xc; xc.x = xls[0]; xc.y = xls[1];
    float tr0 = 0.0f, tr1 = 0.0f, tr2 = 0.0f, tr3 = 0.0f;

#define SSTEP(xv, tl_) { \
    const float lf = dpp_from_lower(u.y); \
    const float rt = dpp_from_upper(u.x); \
    v2f cross; cross.x = lf + u.y; cross.y = u.x + rt; \
    const v2f r = C1v * u + C3v * cross + C2v * uo + svec * (xv) + fv; \
    uo = u; u = r; \
    lane_store(tr0, pel0 ? u.y : u.x, pyl0, (tl_), l); \
    lane_store(tr1, pel1 ? u.y : u.x, pyl1, (tl_), l); \
    lane_store(tr2, pel2 ? u.y : u.x, pyl2, (tl_), l); \
    lane_store(tr3, pel3 ? u.y : u.x, pyl3, (tl_), l); \
}

#pragma unroll 1
    for (int t = 0; t < T_STEPSD; t += 2) {
        const v2f xn = *(const v2f*)&xls[t + 2];   // 2-ahead: hides ds latency
        const int tl = t & 63;
        SSTEP(xc.x, tl)
        SSTEP(xc.y, tl + 1)
        xc = xn;
        if (tl == 62) {                            // chunk (t>>6) complete
            const int ch = t >> 6;
            ltr[wid][0][ch][l] = tr0;
            ltr[wid][1][ch][l] = tr1;
            ltr[wid][2][ch][l] = tr2;
            ltr[wid][3][ch][l] = tr3;
        }
    }
#undef SSTEP

    __syncthreads();

    // Block reduces its 4 modes (wx-weighted) and stores UNCONDITIONALLY to
    // its private pbuf region -- no init required, no atomics, idempotent.
#pragma unroll
    for (int r = 0; r < 4; ++r) {
        const int jc = (tid >> 6) + r * 4;         // j = jc&3, ch = jc>>2
        const int j = jc & 3, ch = jc >> 2;
        const float s = lwx[0][j] * ltr[0][j][ch][l]
                      + lwx[1][j] * ltr[1][j][ch][l]
                      + lwx[2][j] * ltr[2][j][ch][l]
                      + lwx[3][j] * ltr[3][j][ch][l];
        pbuf[((size_t)blockIdx.x * 16 + jc) * 64 + l] = s;
    }
}

// 32 blocks, one per (probe j, batch b). Spectral case: sum the 32 q-regions
// per t (wave-coalesced 256B segments), square-sum over t, write partial.
// Output stage fused via completion counter (zeroed by wave_sim_full, which
// runs before us in stream order): the 32nd block to finish computes out[].
// Fallback case (flag!=0): partial was written by wave_sim_full; blocks skip
// straight to the counter.
__global__ __launch_bounds__(256) void spectral_final(
        const float* __restrict__ pbuf, float* __restrict__ partial,
        const int* __restrict__ flag, int* __restrict__ counter,
        float* __restrict__ out)
{
    __shared__ float sw[4];
    __shared__ int lastsh;
    const int tid = threadIdx.x;
    const int jb = blockIdx.x;          // j = jb>>3, b = jb&7
    const int j = jb >> 3, b = jb & 7;

    if (*flag == 0) {
        const int ch = tid >> 6, l = tid & 63;   // t = ch*64 + l
        float v = 0.0f;
#pragma unroll 8
        for (int q = 0; q < 32; ++q)
            v += pbuf[(((size_t)(b * 32 + q)) * 16 + ch * 4 + j) * 64 + l];
        float acc = v * v;
        for (int off = 32; off; off >>= 1) acc += __shfl_down(acc, off, 64);
        if (l == 0) sw[ch] = acc;
        __syncthreads();
        if (tid == 0) partial[b * N_PROBESD + j] = sw[0] + sw[1] + sw[2] + sw[3];
    }
    __syncthreads();
    if (tid == 0) {
        __threadfence();                 // partial visible before counter bump
        const int done = __hip_atomic_fetch_add(counter, 1, __ATOMIC_ACQ_REL,
                                                __HIP_MEMORY_SCOPE_AGENT);
        lastsh = (done == 31) ? 1 : 0;
    }
    __syncthreads();
    if (lastsh) {
        __threadfence();                 // acquire other blocks' partial
        if (tid < N_PROBESD) {
            float s = 0.0f, tot = 0.0f;
            for (int b2 = 0; b2 < BATCHD; ++b2) s += partial[b2 * N_PROBESD + tid];
            for (int i2 = 0; i2 < BATCHD * N_PROBESD; ++i2) tot += partial[i2];
            out[tid] = s / tot;
        }
    }
}

// ================= FDTD PATH (arbitrary c): round-4 kernel =================
// When flag != nullptr it ALSO performs the c-uniformity check (all blocks
// compute the same verdict; same-value flag store race is benign), zeroes the
// completion counter for spectral_final, and early-exits if c == 1 everywhere.
#define ROW(up, dn, Yr, Zr, Kr) { \
    const float lf = dpp_from_lower((Yr).y); \
    const float rt = dpp_from_upper((Yr).x); \
    v2f cross; cross.x = lf + (Yr).y; cross.y = (Yr).x + rt; \
    const v2f lap = (up) + (dn) + cross - 4.0f * (Yr); \
    (Zr) = (Kr) * lap + (C2v + K2v * (Zr)); \
}

#define PSEL8(ro, Z, pv) switch (ro) { \
    case 0: pv = (Z##0); break; case 1: pv = (Z##1); break; \
    case 2: pv = (Z##2); break; case 3: pv = (Z##3); break; \
    case 4: pv = (Z##4); break; case 5: pv = (Z##5); break; \
    case 6: pv = (Z##6); break; default: pv = (Z##7); break; }

#define STEP8(Y, Z, tt, xsv) { \
    const int buf_ = (tt) & 1, nb_ = buf_ ^ 1; \
    const v2f ra = *(const v2f*)&haloBot[buf_][wa][colb]; \
    const v2f rb = *(const v2f*)&haloTop[buf_][wb][colb]; \
    ROW(Y##1,  Y##3,  Y##2,  Z##2,  k2) \
    ROW(Y##2,  Y##4,  Y##3,  Z##3,  k3) \
    ROW(Y##3,  Y##5,  Y##4,  Z##4,  k4) \
    ROW(ra,    Y##1,  Y##0,  Z##0,  k0) \
    if (has_src) { if (own_src) (Z##0).x += (xsv); } \
    *(v2f*)&haloTop[nb_][w][colb] = (Z##0); \
    ROW(Y##6,  rb,    Y##7,  Z##7,  k7) \
    *(v2f*)&haloBot[nb_][w][colb] = (Z##7); \
    ROW(Y##0,  Y##2,  Y##1,  Z##1,  k1) \
    ROW(Y##4,  Y##6,  Y##5,  Z##5,  k5) \
    ROW(Y##5,  Y##7,  Y##6,  Z##6,  k6) \
    if (anyprobe) { \
        acc8_0 += (Z##0) * (Z##0); acc8_1 += (Z##1) * (Z##1); \
        acc8_2 += (Z##2) * (Z##2); acc8_3 += (Z##3) * (Z##3); \
        acc8_4 += (Z##4) * (Z##4); acc8_5 += (Z##5) * (Z##5); \
        acc8_6 += (Z##6) * (Z##6); acc8_7 += (Z##7) * (Z##7); \
    } \
    __syncthreads(); \
}

__global__ __launch_bounds__(1024, 4) void wave_sim_full(
        const float* __restrict__ x, const float* __restrict__ c,
        const int* __restrict__ probes, float* __restrict__ partial,
        int* __restrict__ flag, int* __restrict__ counter)
{
    const int tid = threadIdx.x;

    if (flag) {
        if (counter && blockIdx.x == 0 && tid == 0) *counter = 0;
        // c-uniformity check: block-uniform verdict, early-exit if spectral.
        __shared__ int wbad[16];
        __shared__ int bad_sh;
        bool bad = false;
        for (int i = tid; i < NXD * NYD; i += 1024) bad |= (c[i] != 1.0f);
        const unsigned long long wb_ = __ballot(bad);
        if ((tid & 63) == 0) wbad[tid >> 6] = (wb_ != 0ULL) ? 1 : 0;
        __syncthreads();
        if (tid == 0) {
            int f = 0;
            for (int i = 0; i < 16; ++i) f |= wbad[i];
            bad_sh = f;
            *flag = f;                  // all blocks store the same value
        }
        __syncthreads();
        if (bad_sh == 0) return;        // spectral path owns the answer
    }

    __shared__ float haloTop[2][17][NYD];
    __shared__ float haloBot[2][17][NYD];
    __shared__ float xs[T_STEPSD];

    const int w = tid >> 6;
    const int l = tid & 63;
    const int b = blockIdx.x;

    const float dt = 0.5f, bdamp = 0.005f;
    const float denom = 1.0f / (dt * dt) + 0.5f * bdamp / dt;
    const float inv_denom = 1.0f / denom;
    const float C2 = 2.0f * inv_denom;
    const float K2 = (-1.0f - dt * bdamp) * inv_denom;
    const float KL = dt * dt * inv_denom;
    v2f C2v; C2v.x = C2; C2v.y = C2;
    v2f K2v; K2v.x = K2; K2v.y = K2;

    for (int i = tid; i < 2 * 17 * NYD; i += 1024) {
        ((float*)haloTop)[i] = 0.0f;
        ((float*)haloBot)[i] = 0.0f;
    }
    if (tid < T_STEPSD) xs[tid] = x[tid * BATCHD + b];

    const int rowbase = w * 8;
    const int colb = 2 * l;
#define LOADK(r) \
    v2f k##r; { \
        const v2f cc = *(const v2f*)&c[(rowbase + r) * NYD + colb]; \
        k##r = KL * cc * cc; \
    }
    LOADK(0) LOADK(1) LOADK(2) LOADK(3) LOADK(4) LOADK(5) LOADK(6) LOADK(7)
#undef LOADK

    v2f zz; zz.x = 0.0f; zz.y = 0.0f;
    v2f a0 = zz, a1 = zz, a2 = zz, a3 = zz, a4 = zz, a5 = zz, a6 = zz, a7 = zz;
    v2f b0 = zz, b1 = zz, b2 = zz, b3 = zz, b4 = zz, b5 = zz, b6 = zz, b7 = zz;
    v2f acc8_0 = zz, acc8_1 = zz, acc8_2 = zz, acc8_3 = zz,
        acc8_4 = zz, acc8_5 = zz, acc8_6 = zz, acc8_7 = zz;

    const int px0 = probes[0] & 127, py0 = probes[1] & 127;
    const int px1 = probes[2] & 127, py1 = probes[3] & 127;
    const int px2 = probes[4] & 127, py2 = probes[5] & 127;
    const int px3 = probes[6] & 127, py3 = probes[7] & 127;
    const bool own0 = ((px0 >> 3) == w) && ((py0 >> 1) == l);
    const bool own1 = ((px1 >> 3) == w) && ((py1 >> 1) == l);
    const bool own2 = ((px2 >> 3) == w) && ((py2 >> 1) == l);
    const bool own3 = ((px3 >> 3) == w) && ((py3 >> 1) == l);
    const bool anyprobe = __ballot(own0 | own1 | own2 | own3) != 0ULL;
    const int pro0s = __builtin_amdgcn_readfirstlane(px0 & 7);
    const int pro1s = __builtin_amdgcn_readfirstlane(px1 & 7);
    const int pro2s = __builtin_amdgcn_readfirstlane(px2 & 7);
    const int pro3s = __builtin_amdgcn_readfirstlane(px3 & 7);
    const int pel0 = py0 & 1, pel1 = py1 & 1, pel2 = py2 & 1, pel3 = py3 & 1;

    const bool has_src = (w == (SRC_XD >> 3));
    const bool own_src = has_src && (l == (SRC_YD >> 1));

    const int wa = (w == 0) ? 16 : w - 1;
    const int wb = (w == 15) ? 16 : w + 1;

    __syncthreads();

#pragma unroll 1
    for (int t = 0; t < T_STEPSD; t += 2) {
        const v2f xp = *(const v2f*)&xs[t];
        STEP8(a, b, t, xp.x)
        STEP8(b, a, t + 1, xp.y)
    }

    if (own0) { v2f pv; PSEL8(pro0s, acc8_, pv) partial[b * N_PROBESD + 0] = pel0 ? pv.y : pv.x; }
    if (own1) { v2f pv; PSEL8(pro1s, acc8_, pv) partial[b * N_PROBESD + 1] = pel1 ? pv.y : pv.x; }
    if (own2) { v2f pv; PSEL8(pro2s, acc8_, pv) partial[b * N_PROBESD + 2] = pel2 ? pv.y : pv.x; }
    if (own3) { v2f pv; PSEL8(pro3s, acc8_, pv) partial[b * N_PROBESD + 3] = pel3 ? pv.y : pv.x; }
}

__global__ void reduce_k(const float* __restrict__ partial, float* __restrict__ out) {
    const int p = threadIdx.x;
    if (p < N_PROBESD) {
        float s = 0.0f, tot = 0.0f;
        for (int bb = 0; bb < BATCHD; ++bb) s += partial[bb * N_PROBESD + p];
        for (int i = 0; i < BATCHD * N_PROBESD; ++i) tot += partial[i];
        out[p] = s / tot;
    }
}

// d_ws layout: [0..4) flag | [4..8) counter | [256..256+1MB) pbuf
// (unconditionally written) | then partial (32 f32). No memset anywhere.
extern "C" void kernel_launch(void* const* d_in, const int* in_sizes, int n_in,
                              void* d_out, int out_size, void* d_ws, size_t ws_size,
                              hipStream_t stream) {
    const float* x      = (const float*)d_in[0];
    const float* c      = (const float*)d_in[1];
    const int*   probes = (const int*)d_in[2];
    float* out = (float*)d_out;

    const size_t pbuf_off = 256;
    const size_t pbuf_bytes = (size_t)256 * 16 * 64 * sizeof(float);   // 1 MB
    const size_t part_off = pbuf_off + pbuf_bytes;
    const size_t need = part_off + 32 * sizeof(float);
    if (ws_size >= need) {
        int*   flag    = (int*)d_ws;
        int*   counter = (int*)d_ws + 1;
        float* pbuf    = (float*)((char*)d_ws + pbuf_off);
        float* partial = (float*)((char*)d_ws + part_off);
        spectral_evolve<<<256, 256, 0, stream>>>(x, probes, pbuf);
        wave_sim_full<<<BATCHD, 1024, 0, stream>>>(x, c, probes, partial, flag, counter);
        spectral_final<<<32, 256, 0, stream>>>(pbuf, partial, flag, counter, out);
    } else {
        float* partial = (float*)d_ws;
        wave_sim_full<<<BATCHD, 1024, 0, stream>>>(x, c, probes, partial, nullptr, nullptr);
        reduce_k<<<1, 64, 0, stream>>>(partial, out);
    }
}